// Round 1
// baseline (278.297 us; speedup 1.0000x reference)
//
#include <hip/hip_runtime.h>
#include <hip/hip_bf16.h>
#include <stdint.h>

using bf16 = __hip_bfloat16;
typedef __bf16 bf16x8 __attribute__((ext_vector_type(8)));
typedef float f32x4 __attribute__((ext_vector_type(4)));
typedef unsigned short u16x8 __attribute__((ext_vector_type(8)));

#define BMT 128
#define BNT 128
#define BKT 64

__device__ inline unsigned short f2b(float f) {
    union { __hip_bfloat16 h; unsigned short u; } cv;
    cv.h = __float2bfloat16(f);
    return cv.u;
}

// ---------------- fp32 -> bf16 convert (vector 8) ----------------
__global__ __launch_bounds__(256) void cvt_f32_bf16(const float* __restrict__ in,
                                                    u16x8* __restrict__ out, long n8) {
    long i = (long)blockIdx.x * blockDim.x + threadIdx.x;
    const long stride = (long)gridDim.x * blockDim.x;
    const float4* in4 = (const float4*)in;
    for (; i < n8; i += stride) {
        float4 a = in4[2 * i], b = in4[2 * i + 1];
        u16x8 o;
        o[0] = f2b(a.x); o[1] = f2b(a.y); o[2] = f2b(a.z); o[3] = f2b(a.w);
        o[4] = f2b(b.x); o[5] = f2b(b.y); o[6] = f2b(b.z); o[7] = f2b(b.w);
        out[i] = o;
    }
}

// ---------------- output store helper ----------------
template <typename T> __device__ inline void storev(T* p, float v);
template <> __device__ inline void storev<float>(float* p, float v) { *p = v; }
template <> __device__ inline void storev<bf16>(bf16* p, float v) { *p = __float2bfloat16(v); }

// ---------------- GEMM: C = A(MxK) * B^T(NxK) [+bias] [*scale] ----------------
// A row-major [M,K] lda, B row-major [N,K] ldb (i.e. B-transposed layout),
// C row-major [M,N] ldc. Optional per-batch strides via blockIdx.z.
// SCORES: skip blocks strictly above the diagonal (causal).
// PVLIM:  limit k-tiles to the causal bound of this row-block.
template <typename OutT, bool HAS_BIAS, bool SCORES, bool PVLIM>
__global__ __launch_bounds__(256) void gemm_bt(
    const bf16* __restrict__ A, long sAb,
    const bf16* __restrict__ B, long sBb,
    OutT* __restrict__ C, long sCb,
    const float* __restrict__ bias, float scale,
    int M, int N, int K, int lda, int ldb, int ldc)
{
    const int bn = blockIdx.x, bm = blockIdx.y, bz = blockIdx.z;
    if (SCORES && bn > bm) return;
    A += (long)bz * sAb;
    B += (long)bz * sBb;
    C += (long)bz * sCb;

    __shared__ __align__(16) bf16 As[BMT][BKT];
    __shared__ __align__(16) bf16 Bs[BNT][BKT];

    const int tid = threadIdx.x;
    const int lane = tid & 63;
    const int wid = tid >> 6;
    const int wr = wid >> 1, wc = wid & 1;

    f32x4 acc[4][4] = {};

    int ktiles = K / BKT;
    if (PVLIM) {
        int lim = (bm + 1) * (BMT / BKT);
        ktiles = ktiles < lim ? ktiles : lim;
    }

    const int srow = tid >> 3;            // 0..31
    const int scol = (tid & 7) * 8;       // 0..56
    const long arow0 = (long)bm * BMT + srow;
    const long brow0 = (long)bn * BNT + srow;

    char* AsB = (char*)&As[0][0];
    char* BsB = (char*)&Bs[0][0];

    for (int kt = 0; kt < ktiles; ++kt) {
        const int kcol = kt * BKT + scol;
#pragma unroll
        for (int i = 0; i < 4; ++i) {
            const bf16* gA = A + (arow0 + 32 * i) * lda + kcol;
            const bf16* gB = B + (brow0 + 32 * i) * ldb + kcol;
            __builtin_amdgcn_global_load_lds(
                (const __attribute__((address_space(1))) void*)gA,
                (__attribute__((address_space(3))) void*)(AsB + i * 4096 + tid * 16), 16, 0, 0);
            __builtin_amdgcn_global_load_lds(
                (const __attribute__((address_space(1))) void*)gB,
                (__attribute__((address_space(3))) void*)(BsB + i * 4096 + tid * 16), 16, 0, 0);
        }
        __syncthreads();   // compiler drains vmcnt before s_barrier

#pragma unroll
        for (int kk = 0; kk < 2; ++kk) {
            bf16x8 af[4], bfr[4];
            const int ko = kk * 32 + ((lane >> 4) * 8);
            const int rA = wr * 64 + (lane & 15);
            const int rB = wc * 64 + (lane & 15);
#pragma unroll
            for (int mi = 0; mi < 4; ++mi) af[mi] = *(const bf16x8*)&As[rA + mi * 16][ko];
#pragma unroll
            for (int ni = 0; ni < 4; ++ni) bfr[ni] = *(const bf16x8*)&Bs[rB + ni * 16][ko];
#pragma unroll
            for (int mi = 0; mi < 4; ++mi)
#pragma unroll
                for (int ni = 0; ni < 4; ++ni)
                    acc[mi][ni] = __builtin_amdgcn_mfma_f32_16x16x32_bf16(
                        af[mi], bfr[ni], acc[mi][ni], 0, 0, 0);
        }
        __syncthreads();
    }

    // epilogue: C/D layout col=lane&15, row=(lane>>4)*4+j
    const int r0 = bm * BMT + wr * 64 + ((lane >> 4) * 4);
    const int c0 = bn * BNT + wc * 64 + (lane & 15);
#pragma unroll
    for (int ni = 0; ni < 4; ++ni) {
        const int c = c0 + ni * 16;
        float bv = 0.0f;
        if (HAS_BIAS) bv = bias[c];
#pragma unroll
        for (int mi = 0; mi < 4; ++mi) {
#pragma unroll
            for (int j = 0; j < 4; ++j) {
                const long r = r0 + mi * 16 + j;
                storev<OutT>(&C[r * (long)ldc + c], acc[mi][ni][j] * scale + bv);
            }
        }
    }
}

// ---------------- causal row softmax, in place on bf16 scores ----------------
// Row i has L=i+1 valid entries (scores already scaled by TAU/sqrt(d)).
// Writes P for j<=i, zero-fills (i, roundup(i+1,128)) so the k-limited PV
// GEMM only ever reads defined data.
__global__ __launch_bounds__(256) void softmax_causal(bf16* __restrict__ SP, int S) {
    const int i = blockIdx.x;
    bf16* row = SP + ((long)blockIdx.y * S + i) * (long)S;
    const int L = i + 1;
    const int tid = threadIdx.x;
    const int lane = tid & 63, wid = tid >> 6;

    float v[8];
    int nv = 0;
    float m = -3.0e38f;
    for (int j = tid; j < L; j += 256) {
        float x = __bfloat162float(row[j]);
        v[nv++] = x;
        m = fmaxf(m, x);
    }
#pragma unroll
    for (int d = 32; d; d >>= 1) m = fmaxf(m, __shfl_xor(m, d));
    __shared__ float redm[4], reds[4];
    if (lane == 0) redm[wid] = m;
    __syncthreads();
    m = fmaxf(fmaxf(redm[0], redm[1]), fmaxf(redm[2], redm[3]));

    float s = 0.f;
    for (int t = 0; t < nv; ++t) { v[t] = __expf(v[t] - m); s += v[t]; }
#pragma unroll
    for (int d = 32; d; d >>= 1) s += __shfl_xor(s, d);
    if (lane == 0) reds[wid] = s;
    __syncthreads();
    s = reds[0] + reds[1] + reds[2] + reds[3];
    const float inv = 1.0f / s;

    nv = 0;
    for (int j = tid; j < L; j += 256) row[j] = __float2bfloat16(v[nv++] * inv);
    const int Lpad = ((i >> 7) + 1) << 7;
    for (int j = L + tid; j < Lpad; j += 256) row[j] = __float2bfloat16(0.0f);
}

// ---------------- bf16 transpose [S,D] -> [D,S] per batch ----------------
__global__ __launch_bounds__(256) void transpose2d(const bf16* __restrict__ V,
                                                   bf16* __restrict__ Vt, int S, int D) {
    __shared__ bf16 t[64][72];
    const long bo = (long)blockIdx.z * (long)S * D;
    const int d0 = blockIdx.x * 64, s0 = blockIdx.y * 64;
    const int tid = threadIdx.x;
    const int r = tid >> 3, c8 = (tid & 7) * 8;
#pragma unroll
    for (int it = 0; it < 2; ++it) {
        const int row = r + it * 32;
        u16x8 val = *(const u16x8*)&V[bo + (long)(s0 + row) * D + d0 + c8];
#pragma unroll
        for (int e = 0; e < 8; ++e) {
            union { unsigned short u; bf16 h; } cv; cv.u = val[e];
            t[row][c8 + e] = cv.h;
        }
    }
    __syncthreads();
#pragma unroll
    for (int it = 0; it < 2; ++it) {
        const int dr = r + it * 32;
        u16x8 o;
#pragma unroll
        for (int e = 0; e < 8; ++e) {
            union { unsigned short u; bf16 h; } cv; cv.h = t[c8 + e][dr];
            o[e] = cv.u;
        }
        *(u16x8*)&Vt[bo + (long)(d0 + dr) * S + s0 + c8] = o;
    }
}

extern "C" void kernel_launch(void* const* d_in, const int* in_sizes, int n_in,
                              void* d_out, int out_size, void* d_ws, size_t ws_size,
                              hipStream_t stream) {
    const int B = 4, S = 2048, D = 1024;
    const long MD = (long)B * S * D;        // 8,388,608
    const float scale = 0.5f / 32.0f;       // TAU / sqrt(D)

    const float* node  = (const float*)d_in[0];
    const float* label = (const float*)d_in[1];
    const float* Wq = (const float*)d_in[2];
    const float* bq = (const float*)d_in[3];
    const float* Wk = (const float*)d_in[4];
    const float* bk = (const float*)d_in[5];
    const float* Wv = (const float*)d_in[6];
    const float* bv = (const float*)d_in[7];
    const float* Wp = (const float*)d_in[8];
    const float* bp = (const float*)d_in[9];
    float* out = (float*)d_out;

    // ---- workspace layout (bytes), with aliasing:
    //   [0,16M)       nodeb
    //   [16M,32M)     labelb  (dead after Q gemm)  -> Z
    //   [32M,40M)     Wq/Wk/Wv/Wp bf16
    //   [40M,56M)     Q       (dead after scores)  -> Vt
    //   [56M,72M)     K
    //   [72M,88M)     V
    //   [88M,120M)    scores bf16 -> P (in-place)
    char* ws = (char*)d_ws;
    bf16* nodeb  = (bf16*)(ws);
    bf16* labelb = (bf16*)(ws + 16777216);
    bf16* Zb     = labelb;                         // alias
    bf16* Wqb = (bf16*)(ws + 33554432);
    bf16* Wkb = (bf16*)(ws + 35651584);
    bf16* Wvb = (bf16*)(ws + 37748736);
    bf16* Wpb = (bf16*)(ws + 39845888);
    bf16* Qb  = (bf16*)(ws + 41943040);
    bf16* Vtb = Qb;                                // alias (transpose runs after scores)
    bf16* Kb  = (bf16*)(ws + 58720256);
    bf16* Vb  = (bf16*)(ws + 75497472);
    bf16* SP  = (bf16*)(ws + 92274688);            // B*S*S bf16 = 33,554,432 B
    if (ws_size < 125829120UL) return;             // refuse to scribble

    dim3 blk(256);

    // fp32 -> bf16 converts
    cvt_f32_bf16<<<1024, blk, 0, stream>>>(node,  (u16x8*)nodeb,  MD / 8);
    cvt_f32_bf16<<<1024, blk, 0, stream>>>(label, (u16x8*)labelb, MD / 8);
    cvt_f32_bf16<<<256, blk, 0, stream>>>(Wq, (u16x8*)Wqb, (long)D * D / 8);
    cvt_f32_bf16<<<256, blk, 0, stream>>>(Wk, (u16x8*)Wkb, (long)D * D / 8);
    cvt_f32_bf16<<<256, blk, 0, stream>>>(Wv, (u16x8*)Wvb, (long)D * D / 8);
    cvt_f32_bf16<<<256, blk, 0, stream>>>(Wp, (u16x8*)Wpb, (long)D * D / 8);

    // projections: X @ W.T + b   (M=B*S=8192, N=K=D=1024)
    dim3 gproj(D / BNT, (B * S) / BMT, 1);
    gemm_bt<bf16, true, false, false><<<gproj, blk, 0, stream>>>(
        labelb, 0, Wqb, 0, Qb, 0, bq, 1.0f, B * S, D, D, D, D, D);
    gemm_bt<bf16, true, false, false><<<gproj, blk, 0, stream>>>(
        nodeb, 0, Wkb, 0, Kb, 0, bk, 1.0f, B * S, D, D, D, D, D);
    gemm_bt<bf16, true, false, false><<<gproj, blk, 0, stream>>>(
        nodeb, 0, Wvb, 0, Vb, 0, bv, 1.0f, B * S, D, D, D, D, D);

    // scores = (Q @ K^T) * (TAU/sqrt(d)), causal upper blocks skipped
    dim3 gsc(S / BNT, S / BMT, B);
    gemm_bt<bf16, false, true, false><<<gsc, blk, 0, stream>>>(
        Qb, (long)S * D, Kb, (long)S * D, SP, (long)S * S, nullptr, scale,
        S, S, D, D, D, S);

    // V^T (per batch) for the PV gemm's B^T layout
    dim3 gtr(D / 64, S / 64, B);
    transpose2d<<<gtr, blk, 0, stream>>>(Vb, Vtb, S, D);

    // causal softmax in-place: scores -> P (bf16)
    softmax_causal<<<dim3(S, B), blk, 0, stream>>>(SP, S);

    // Z = P @ V  (as P @ Vt^T), k-tiles causally limited per row-block
    dim3 gpv(D / BNT, S / BMT, B);
    gemm_bt<bf16, false, false, true><<<gpv, blk, 0, stream>>>(
        SP, (long)S * S, Vtb, (long)S * D, Zb, (long)S * D, nullptr, 1.0f,
        S, D, S, S, S, D);

    // out = Z @ Wp^T + bp (fp32 out)
    gemm_bt<float, true, false, false><<<gproj, blk, 0, stream>>>(
        Zb, 0, Wpb, 0, out, 0, bp, 1.0f, B * S, D, D, D, D, D);
}

// Round 2
// 234.835 us; speedup vs baseline: 1.1851x; 1.1851x over previous
//
#include <hip/hip_runtime.h>
#include <hip/hip_bf16.h>
#include <stdint.h>

using bf16 = __hip_bfloat16;
typedef __bf16 bf16x8 __attribute__((ext_vector_type(8)));
typedef float f32x4 __attribute__((ext_vector_type(4)));
typedef unsigned short u16x8 __attribute__((ext_vector_type(8)));

#define GBM 256
#define GBN 128
#define GBK 64
// LDS per buffer: A 256x64x2B = 32768, B 128x64x2B = 16384 -> 49152; x2 = 98304

__device__ inline unsigned short f2b(float f) {
    union { __hip_bfloat16 h; unsigned short u; } cv;
    cv.h = __float2bfloat16(f);
    return cv.u;
}

// ---------------- fp32 -> bf16 convert (vector 8) ----------------
__global__ __launch_bounds__(256) void cvt_f32_bf16(const float* __restrict__ in,
                                                    u16x8* __restrict__ out, long n8) {
    long i = (long)blockIdx.x * blockDim.x + threadIdx.x;
    const long stride = (long)gridDim.x * blockDim.x;
    const float4* in4 = (const float4*)in;
    for (; i < n8; i += stride) {
        float4 a = in4[2 * i], b = in4[2 * i + 1];
        u16x8 o;
        o[0] = f2b(a.x); o[1] = f2b(a.y); o[2] = f2b(a.z); o[3] = f2b(a.w);
        o[4] = f2b(b.x); o[5] = f2b(b.y); o[6] = f2b(b.z); o[7] = f2b(b.w);
        out[i] = o;
    }
}

template <typename T> __device__ inline void storev(T* p, float v);
template <> __device__ inline void storev<float>(float* p, float v) { *p = v; }
template <> __device__ inline void storev<bf16>(bf16* p, float v) { *p = __float2bfloat16(v); }

// ---------------- pipelined GEMM: C = A(MxK) * B^T(NxK) ----------------
// 256x128 tile, BK=64, 8 waves (4M x 2N), per-wave 64x64 output.
// Double-buffered LDS, counted vmcnt(6) across barriers, XOR-swizzled LDS
// (linear global_load_lds dest + inverse-swizzled global source + swizzled read).
// MODE 0: QKV fused (bn segment selects A/C/bias; B rows = stacked Wq|Wk|Wv)
// MODE 1: causal scores (flat-decoded lower-triangle grid, batch via z)
// MODE 2: PV with causal k-limit (batch via z)
// MODE 3: plain + bias (output projection)
template <typename OutT, int MODE>
__global__ __launch_bounds__(512) void gemm8(
    const bf16* __restrict__ A0, const bf16* __restrict__ A1,
    const bf16* __restrict__ Bw,
    OutT* __restrict__ C0, OutT* __restrict__ C1, OutT* __restrict__ C2,
    const float* __restrict__ b0, const float* __restrict__ b1, const float* __restrict__ b2,
    float scale, int K, int lda, int ldb, int ldc,
    long sA, long sB, long sC)
{
    __shared__ __align__(16) char lds[98304];

    int bm, bn;
    const bf16* A;
    const bf16* B;
    OutT* C;
    const float* bias = nullptr;
    int ccol0;

    if (MODE == 0) {
        bn = blockIdx.x; bm = blockIdx.y;
        const int seg = bn >> 3, bnl = bn & 7;
        A = (seg == 0) ? A0 : A1;
        B = Bw;                                      // stacked weight rows
        C = (seg == 0) ? C0 : (seg == 1 ? C1 : C2);
        bias = (seg == 0) ? b0 : (seg == 1 ? b1 : b2);
        ccol0 = bnl * GBN;
    } else if (MODE == 1) {
        const int f = blockIdx.x, z = blockIdx.z;
        int m = (int)((-1.0f + sqrtf(1.0f + 4.0f * (float)f)) * 0.5f);
        while ((m + 1) * (m + 2) <= f) ++m;
        while (m * (m + 1) > f) --m;
        bm = m; bn = f - m * (m + 1);                // bn in [0, 2bm+2)
        A = A0 + (long)z * sA; B = Bw + (long)z * sB; C = C0 + (long)z * sC;
        ccol0 = bn * GBN;
    } else if (MODE == 2) {
        bn = blockIdx.x; bm = blockIdx.y;
        const int z = blockIdx.z;
        A = A0 + (long)z * sA; B = Bw + (long)z * sB; C = C0 + (long)z * sC;
        ccol0 = bn * GBN;
    } else {
        bn = blockIdx.x; bm = blockIdx.y;
        A = A0; B = Bw; C = C0; bias = b0;
        ccol0 = bn * GBN;
    }

    int KT = K / GBK;
    if (MODE == 2) { const int lim = 4 * (bm + 1); if (lim < KT) KT = lim; }

    const int tid = threadIdx.x;
    const int lane = tid & 63;
    const int w = tid >> 6;
    const int wm = w >> 1, wn = w & 1;

    const int rowA0 = bm * GBM;
    const int rowB0 = bn * GBN;

    // ---- staging constants (linear LDS dest; inverse-swizzled global source)
    const int rr  = tid >> 3;                    // LDS row within 64-row round
    const int pch = tid & 7;                     // physical 16B chunk in row
    const int lch = pch ^ (rr & 7);              // logical chunk (row&7 == rr&7)
    const bf16* gA = A + (long)(rowA0 + rr) * lda + lch * 8;
    const bf16* gB = B + (long)(rowB0 + rr) * ldb + lch * 8;

    auto STAGE = [&](int kt, int d) {
        char* la = lds + d * 49152;
        char* lb = la + 32768;
        const bf16* ga = gA + kt * GBK;
        const bf16* gb = gB + kt * GBK;
#pragma unroll
        for (int i = 0; i < 4; ++i)
            __builtin_amdgcn_global_load_lds(
                (const __attribute__((address_space(1))) void*)(ga + (long)i * 64 * lda),
                (__attribute__((address_space(3))) void*)(la + i * 8192 + tid * 16), 16, 0, 0);
#pragma unroll
        for (int i = 0; i < 2; ++i)
            __builtin_amdgcn_global_load_lds(
                (const __attribute__((address_space(1))) void*)(gb + (long)i * 64 * ldb),
                (__attribute__((address_space(3))) void*)(lb + i * 8192 + tid * 16), 16, 0, 0);
    };

    // ---- fragment read addressing (swizzled)
    const int arow = wm * 64 + (lane & 15);      // + mi*16
    const int brow = wn * 64 + (lane & 15);      // + ni*16
    const int csw  = (lane & 7) << 4;
    const int cb0  = (lane >> 4) << 4;

#define RDA(la_, mi, kk) (*(const bf16x8*)((la_) + (arow + (mi)*16) * 128 + ((((kk)*64) + cb0) ^ csw)))
#define RDB(lb_, ni, kk) (*(const bf16x8*)((lb_) + (brow + (ni)*16) * 128 + ((((kk)*64) + cb0) ^ csw)))
#define MM(mi, ni, a0_, a1_, b0_, b1_) \
    acc[mi][ni] = __builtin_amdgcn_mfma_f32_16x16x32_bf16(a0_, b0_, acc[mi][ni], 0, 0, 0); \
    acc[mi][ni] = __builtin_amdgcn_mfma_f32_16x16x32_bf16(a1_, b1_, acc[mi][ni], 0, 0, 0);

    f32x4 acc[4][4] = {};

    STAGE(0, 0);
    if (KT > 1) STAGE(1, 1);

    for (int t = 0; t < KT; ++t) {
        if (t < KT - 1) asm volatile("s_waitcnt vmcnt(6)" ::: "memory");
        else            asm volatile("s_waitcnt vmcnt(0)" ::: "memory");
        __builtin_amdgcn_s_barrier();
        __builtin_amdgcn_sched_barrier(0);

        const char* la = lds + (t & 1) * 49152;
        const char* lb = la + 32768;

        // q0: A-half0 x B-half0
        bf16x8 A00 = RDA(la,0,0), A01 = RDA(la,0,1), A10 = RDA(la,1,0), A11 = RDA(la,1,1);
        bf16x8 B00 = RDB(lb,0,0), B01 = RDB(lb,0,1), B10 = RDB(lb,1,0), B11 = RDB(lb,1,1);
        __builtin_amdgcn_s_setprio(1);
        MM(0,0, A00,A01, B00,B01); MM(0,1, A00,A01, B10,B11);
        MM(1,0, A10,A11, B00,B01); MM(1,1, A10,A11, B10,B11);
        __builtin_amdgcn_s_setprio(0);

        // q1: A-half0 x B-half1
        bf16x8 B20 = RDB(lb,2,0), B21 = RDB(lb,2,1), B30 = RDB(lb,3,0), B31 = RDB(lb,3,1);
        __builtin_amdgcn_s_setprio(1);
        MM(0,2, A00,A01, B20,B21); MM(0,3, A00,A01, B30,B31);
        MM(1,2, A10,A11, B20,B21); MM(1,3, A10,A11, B30,B31);
        __builtin_amdgcn_s_setprio(0);

        // q2+q3: A-half1 x both B halves (B-half0 kept live)
        bf16x8 A20 = RDA(la,2,0), A21 = RDA(la,2,1), A30 = RDA(la,3,0), A31 = RDA(la,3,1);
        __builtin_amdgcn_s_setprio(1);
        MM(2,2, A20,A21, B20,B21); MM(2,3, A20,A21, B30,B31);
        MM(3,2, A30,A31, B20,B21); MM(3,3, A30,A31, B30,B31);
        MM(2,0, A20,A21, B00,B01); MM(2,1, A20,A21, B10,B11);
        MM(3,0, A30,A31, B00,B01); MM(3,1, A30,A31, B10,B11);
        __builtin_amdgcn_s_setprio(0);

        asm volatile("s_waitcnt lgkmcnt(0)" ::: "memory");
        __builtin_amdgcn_s_barrier();
        __builtin_amdgcn_sched_barrier(0);
        if (t + 2 < KT) STAGE(t + 2, t & 1);     // overwrite just-freed buffer
    }

    // ---- epilogue: C/D layout col=lane&15, row=(lane>>4)*4+j
    const int r0 = rowA0 + wm * 64 + ((lane >> 4) * 4);
    const int c0 = ccol0 + wn * 64 + (lane & 15);
    const bool HB = (MODE == 0 || MODE == 3);
#pragma unroll
    for (int ni = 0; ni < 4; ++ni) {
        const int c = c0 + ni * 16;
        const float bv = HB ? bias[c] : 0.0f;
#pragma unroll
        for (int mi = 0; mi < 4; ++mi) {
#pragma unroll
            for (int j = 0; j < 4; ++j) {
                const long r = r0 + mi * 16 + j;
                storev<OutT>(&C[r * (long)ldc + c], acc[mi][ni][j] * scale + bv);
            }
        }
    }
#undef RDA
#undef RDB
#undef MM
}

// ---------------- causal row softmax, in place on bf16 scores ----------------
// Zero-fills (i, roundup(i+1,256)) so PV's 256-row-block k-limit reads only
// defined data.
__global__ __launch_bounds__(256) void softmax_causal(bf16* __restrict__ SP, int S) {
    const int i = blockIdx.x;
    bf16* row = SP + ((long)blockIdx.y * S + i) * (long)S;
    const int L = i + 1;
    const int tid = threadIdx.x;
    const int lane = tid & 63, wid = tid >> 6;

    float v[8];
    int nv = 0;
    float m = -3.0e38f;
    for (int j = tid; j < L; j += 256) {
        float x = __bfloat162float(row[j]);
        v[nv++] = x;
        m = fmaxf(m, x);
    }
#pragma unroll
    for (int d = 32; d; d >>= 1) m = fmaxf(m, __shfl_xor(m, d));
    __shared__ float redm[4], reds[4];
    if (lane == 0) redm[wid] = m;
    __syncthreads();
    m = fmaxf(fmaxf(redm[0], redm[1]), fmaxf(redm[2], redm[3]));

    float s = 0.f;
    for (int t = 0; t < nv; ++t) { v[t] = __expf(v[t] - m); s += v[t]; }
#pragma unroll
    for (int d = 32; d; d >>= 1) s += __shfl_xor(s, d);
    if (lane == 0) reds[wid] = s;
    __syncthreads();
    s = reds[0] + reds[1] + reds[2] + reds[3];
    const float inv = 1.0f / s;

    nv = 0;
    for (int j = tid; j < L; j += 256) row[j] = __float2bfloat16(v[nv++] * inv);
    const int Lpad = ((i >> 8) + 1) << 8;
    for (int j = L + tid; j < Lpad; j += 256) row[j] = __float2bfloat16(0.0f);
}

// ---------------- bf16 transpose [S,D] -> [D,S] per batch ----------------
__global__ __launch_bounds__(256) void transpose2d(const bf16* __restrict__ V,
                                                   bf16* __restrict__ Vt, int S, int D) {
    __shared__ bf16 t[64][72];
    const long bo = (long)blockIdx.z * (long)S * D;
    const int d0 = blockIdx.x * 64, s0 = blockIdx.y * 64;
    const int tid = threadIdx.x;
    const int r = tid >> 3, c8 = (tid & 7) * 8;
#pragma unroll
    for (int it = 0; it < 2; ++it) {
        const int row = r + it * 32;
        u16x8 val = *(const u16x8*)&V[bo + (long)(s0 + row) * D + d0 + c8];
#pragma unroll
        for (int e = 0; e < 8; ++e) {
            union { unsigned short u; bf16 h; } cv; cv.u = val[e];
            t[row][c8 + e] = cv.h;
        }
    }
    __syncthreads();
#pragma unroll
    for (int it = 0; it < 2; ++it) {
        const int dr = r + it * 32;
        u16x8 o;
#pragma unroll
        for (int e = 0; e < 8; ++e) {
            union { unsigned short u; bf16 h; } cv; cv.h = t[c8 + e][dr];
            o[e] = cv.u;
        }
        *(u16x8*)&Vt[bo + (long)(d0 + dr) * S + s0 + c8] = o;
    }
}

extern "C" void kernel_launch(void* const* d_in, const int* in_sizes, int n_in,
                              void* d_out, int out_size, void* d_ws, size_t ws_size,
                              hipStream_t stream) {
    const int B = 4, S = 2048, D = 1024;
    const long MD = (long)B * S * D;
    const float scale = 0.5f / 32.0f;       // TAU / sqrt(D)

    const float* node  = (const float*)d_in[0];
    const float* label = (const float*)d_in[1];
    const float* Wq = (const float*)d_in[2];
    const float* bq = (const float*)d_in[3];
    const float* Wk = (const float*)d_in[4];
    const float* bk = (const float*)d_in[5];
    const float* Wv = (const float*)d_in[6];
    const float* bv = (const float*)d_in[7];
    const float* Wp = (const float*)d_in[8];
    const float* bp = (const float*)d_in[9];
    float* out = (float*)d_out;

    // ---- workspace layout (bytes), with aliasing:
    //   [0,16M)       nodeb
    //   [16M,32M)     labelb  (dead after QKV gemm)  -> Z
    //   [32M,40M)     Wq|Wk|Wv (contiguous, stacked for fused QKV) then Wp
    //   [40M,56M)     Q       (dead after scores)    -> Vt
    //   [56M,72M)     K
    //   [72M,88M)     V
    //   [88M,120M)    scores bf16 -> P (in-place)
    char* ws = (char*)d_ws;
    bf16* nodeb  = (bf16*)(ws);
    bf16* labelb = (bf16*)(ws + 16777216);
    bf16* Zb     = labelb;                         // alias
    bf16* Wqb = (bf16*)(ws + 33554432);
    bf16* Wkb = (bf16*)(ws + 35651584);
    bf16* Wvb = (bf16*)(ws + 37748736);
    bf16* Wpb = (bf16*)(ws + 39845888);
    bf16* Qb  = (bf16*)(ws + 41943040);
    bf16* Vtb = Qb;                                // alias (transpose after scores)
    bf16* Kb  = (bf16*)(ws + 58720256);
    bf16* Vb  = (bf16*)(ws + 75497472);
    bf16* SP  = (bf16*)(ws + 92274688);
    if (ws_size < 125829120UL) return;

    dim3 blk(256);

    cvt_f32_bf16<<<1024, blk, 0, stream>>>(node,  (u16x8*)nodeb,  MD / 8);
    cvt_f32_bf16<<<1024, blk, 0, stream>>>(label, (u16x8*)labelb, MD / 8);
    cvt_f32_bf16<<<256, blk, 0, stream>>>(Wq, (u16x8*)Wqb, (long)D * D / 8);
    cvt_f32_bf16<<<256, blk, 0, stream>>>(Wk, (u16x8*)Wkb, (long)D * D / 8);
    cvt_f32_bf16<<<256, blk, 0, stream>>>(Wv, (u16x8*)Wvb, (long)D * D / 8);
    cvt_f32_bf16<<<256, blk, 0, stream>>>(Wp, (u16x8*)Wpb, (long)D * D / 8);

    // fused QKV: bn 0..7 -> Q (A=label), 8..15 -> K, 16..23 -> V (A=node)
    gemm8<bf16, 0><<<dim3(24, 32), 512, 0, stream>>>(
        labelb, nodeb, Wqb, Qb, Kb, Vb, bq, bk, bv,
        1.0f, D, D, D, D, 0, 0, 0);

    // causal scores = (Q @ K^T) * (TAU/sqrt(d)); exact lower-triangle grid
    gemm8<bf16, 1><<<dim3(72, 1, 4), 512, 0, stream>>>(
        Qb, nullptr, Kb, SP, nullptr, nullptr, nullptr, nullptr, nullptr,
        scale, D, D, D, S, (long)S * D, (long)S * D, (long)S * S);

    // V^T per batch (into the dead Q buffer)
    dim3 gtr(D / 64, S / 64, B);
    transpose2d<<<gtr, blk, 0, stream>>>(Vb, Vtb, S, D);

    // causal softmax in-place (zero-fill to 256-block boundary)
    softmax_causal<<<dim3(S, B), blk, 0, stream>>>(SP, S);

    // Z = P @ V (as P @ Vt^T), k-tiles causally limited per 256-row block
    gemm8<bf16, 2><<<dim3(8, 8, 4), 512, 0, stream>>>(
        SP, nullptr, Vtb, Zb, nullptr, nullptr, nullptr, nullptr, nullptr,
        1.0f, S, S, S, D, (long)S * S, (long)D * S, (long)S * D);

    // out = Z @ Wp^T + bp (fp32)
    gemm8<float, 3><<<dim3(8, 32), 512, 0, stream>>>(
        Zb, nullptr, Wpb, out, nullptr, nullptr, bp, nullptr, nullptr,
        1.0f, D, D, D, D, 0, 0, 0);
}

// Round 3
// 233.770 us; speedup vs baseline: 1.1905x; 1.0046x over previous
//
#include <hip/hip_runtime.h>
#include <hip/hip_bf16.h>
#include <stdint.h>

using bf16 = __hip_bfloat16;
typedef __bf16 bf16x8 __attribute__((ext_vector_type(8)));
typedef float f32x4 __attribute__((ext_vector_type(4)));
typedef unsigned short u16x8 __attribute__((ext_vector_type(8)));

#define AS1 __attribute__((address_space(1)))
#define AS3 __attribute__((address_space(3)))

__device__ inline unsigned short f2b(float f) {
    union { __hip_bfloat16 h; unsigned short u; } cv;
    cv.h = __float2bfloat16(f);
    return cv.u;
}

// ---------------- fp32 -> bf16 converts ----------------
__global__ __launch_bounds__(256) void cvt_pair(const float* __restrict__ a, const float* __restrict__ b,
                                                u16x8* __restrict__ oa, u16x8* __restrict__ ob, long n8) {
    const float* in = blockIdx.y ? b : a;
    u16x8* out = blockIdx.y ? ob : oa;
    long i = (long)blockIdx.x * blockDim.x + threadIdx.x;
    const long stride = (long)gridDim.x * blockDim.x;
    const float4* in4 = (const float4*)in;
    for (; i < n8; i += stride) {
        float4 x = in4[2 * i], y = in4[2 * i + 1];
        u16x8 o;
        o[0] = f2b(x.x); o[1] = f2b(x.y); o[2] = f2b(x.z); o[3] = f2b(x.w);
        o[4] = f2b(y.x); o[5] = f2b(y.y); o[6] = f2b(y.z); o[7] = f2b(y.w);
        out[i] = o;
    }
}

__global__ __launch_bounds__(256) void cvt_quad(const float* __restrict__ a, const float* __restrict__ b,
                                                const float* __restrict__ c, const float* __restrict__ d,
                                                u16x8* __restrict__ oa, u16x8* __restrict__ ob,
                                                u16x8* __restrict__ oc, u16x8* __restrict__ od, long n8) {
    const int y = blockIdx.y;
    const float* in = y == 0 ? a : (y == 1 ? b : (y == 2 ? c : d));
    u16x8* out = y == 0 ? oa : (y == 1 ? ob : (y == 2 ? oc : od));
    long i = (long)blockIdx.x * blockDim.x + threadIdx.x;
    const long stride = (long)gridDim.x * blockDim.x;
    const float4* in4 = (const float4*)in;
    for (; i < n8; i += stride) {
        float4 x = in4[2 * i], z = in4[2 * i + 1];
        u16x8 o;
        o[0] = f2b(x.x); o[1] = f2b(x.y); o[2] = f2b(x.z); o[3] = f2b(x.w);
        o[4] = f2b(z.x); o[5] = f2b(z.y); o[6] = f2b(z.z); o[7] = f2b(z.w);
        out[i] = o;
    }
}

template <typename T> __device__ inline void storev(T* p, float v);
template <> __device__ inline void storev<float>(float* p, float v) { *p = v; }
template <> __device__ inline void storev<bf16>(bf16* p, float v) { *p = __float2bfloat16(v); }

// ================= 256x256 8-phase GEMM: C = A(MxK) * B^T(NxK) =================
// 8 waves (2M x 4N), per-wave 128x64 output (8x4 frags), BK=64.
// buf0 holds even K-tiles, buf1 odd. Stage unit = 16KB (2 x gload_lds_x4).
// Per-iteration stage plan (tiles t0=2i, t0+1 consumed):
//   P1:SA0(t0+1)->b1  P2:SA1(t0+1)->b1  P3:SB0(t0+2)->b0  P4:SB1(t0+2)->b0
//   P5:SA0(t0+2)->b0  P6:SA1(t0+2)->b0  P7:SB0(t0+3)->b1  P8:SB1(t0+3)->b1
// vmcnt(4) at end-P4 (retires tile t0+1) and end-P8 (retires t0+2); last iter
// stages nothing -> vmcnt(0) at end-P4.
// MODE 0: fused QKV  MODE 1: causal scores  MODE 2: PV (causal k-limit)  MODE 3: proj
template <typename OutT, int MODE>
__global__ __launch_bounds__(512, 2) void gemm256(
    const bf16* __restrict__ A0, const bf16* __restrict__ A1,
    const bf16* __restrict__ Bw,
    OutT* __restrict__ C0, OutT* __restrict__ C1, OutT* __restrict__ C2,
    const float* __restrict__ b0, const float* __restrict__ b1, const float* __restrict__ b2,
    float scale, int K, int lda, int ldb, int ldc,
    long sA, long sB, long sC)
{
    __shared__ __align__(16) char lds[131072];

    // ---- block decode with XCD swizzle (all grids %8 == 0)
    const int nwg = gridDim.x;
    int bid = blockIdx.x;
    int s = (nwg & 7) ? bid : ((bid & 7) * (nwg >> 3) + (bid >> 3));

    int bm, bn, ccol0;
    const bf16* A; const bf16* B; OutT* C;
    const float* bias = nullptr;

    if (MODE == 0) {
        bm = s / 12; bn = s % 12;
        const int seg = bn >> 2;
        A = (seg == 0) ? A0 : A1;
        B = Bw;
        C = (seg == 0) ? C0 : (seg == 1 ? C1 : C2);
        bias = (seg == 0) ? b0 : (seg == 1 ? b1 : b2);
        ccol0 = (bn & 3) * 256;
    } else if (MODE == 1) {
        const int z = s / 36, f = s % 36;
        int m = 0;
        while ((m + 1) * (m + 2) / 2 <= f) ++m;
        bm = m; bn = f - m * (m + 1) / 2;
        A = A0 + (long)z * sA; B = Bw + (long)z * sB; C = C0 + (long)z * sC;
        ccol0 = bn * 256;
    } else if (MODE == 2) {
        const int z = s >> 5, r = s & 31;
        bm = r >> 2; bn = r & 3;
        A = A0 + (long)z * sA; B = Bw + (long)z * sB; C = C0 + (long)z * sC;
        ccol0 = bn * 256;
    } else {
        bm = s >> 2; bn = s & 3;
        A = A0; B = Bw; C = C0; bias = b0;
        ccol0 = bn * 256;
    }

    int KT = K >> 6;
    if (MODE == 2) { const int lim = 4 * (bm + 1); if (lim < KT) KT = lim; }
    const int NIT = KT >> 1;

    const int tid = threadIdx.x;
    const int lane = tid & 63;
    const int w = tid >> 6;
    const int wm = w >> 2, wn = w & 3;

    const int rowA0 = bm * 256;
    const int rowB0 = bn * 256;

    // ---- staging (linear LDS dest, inverse-swizzled global source)
    const int rr  = tid >> 3;
    const int lch = (tid & 7) ^ (rr & 7);
    const bf16* gAt = A + (long)(rowA0 + rr) * lda + lch * 8;
    const bf16* gBt = B + (long)(rowB0 + rr) * ldb + lch * 8;
    char* ldsA[2] = { lds, lds + 65536 };
    char* ldsB[2] = { lds + 32768, lds + 98304 };

    auto SG2 = [&](const bf16* g, int ld, char* dst) {
        __builtin_amdgcn_global_load_lds((const AS1 void*)g,
            (AS3 void*)(dst + tid * 16), 16, 0, 0);
        __builtin_amdgcn_global_load_lds((const AS1 void*)(g + (long)64 * ld),
            (AS3 void*)(dst + 8192 + tid * 16), 16, 0, 0);
    };
    auto ST_A = [&](int kt, int half, int b) {
        SG2(gAt + (long)kt * 64 + (long)half * 128 * lda, lda, ldsA[b] + half * 16384);
    };
    auto ST_B = [&](int kt, int half, int b) {
        SG2(gBt + (long)kt * 64 + (long)half * 128 * ldb, ldb, ldsB[b] + half * 16384);
    };

    // ---- swizzled fragment read addressing
    const int abase = (wm * 128 + (lane & 15)) * 128;
    const int bbase = (wn * 64  + (lane & 15)) * 128;
    const int cc0 = (((lane >> 4) << 4)) ^ ((lane & 7) << 4);
    const int cc1 = cc0 ^ 64;

#define RAF(b, mh, mi, kk) (*(const bf16x8*)(ldsA[b] + abase + (mh)*8192 + (mi)*2048 + ((kk) ? cc1 : cc0)))
#define RBF(b, ni, kk)     (*(const bf16x8*)(ldsB[b] + bbase + (ni)*2048 + ((kk) ? cc1 : cc0)))

    f32x4 acc[8][4] = {};
    bf16x8 ar[4][2], blo[2][2], bhi[2][2];

#define RD_A(b, mh) { _Pragma("unroll") for (int mi = 0; mi < 4; ++mi) { ar[mi][0] = RAF(b, mh, mi, 0); ar[mi][1] = RAF(b, mh, mi, 1); } }
#define RD_BLO(b)   { _Pragma("unroll") for (int ni = 0; ni < 2; ++ni) { blo[ni][0] = RBF(b, ni, 0); blo[ni][1] = RBF(b, ni, 1); } }
#define RD_BHI(b)   { _Pragma("unroll") for (int ni = 0; ni < 2; ++ni) { bhi[ni][0] = RBF(b, 2 + ni, 0); bhi[ni][1] = RBF(b, 2 + ni, 1); } }

#define MQ(bb, MH, NB) \
    _Pragma("unroll") \
    for (int mi = 0; mi < 4; ++mi) { \
        _Pragma("unroll") \
        for (int ni = 0; ni < 2; ++ni) { \
            f32x4 t = acc[(MH)*4 + mi][(NB) + ni]; \
            t = __builtin_amdgcn_mfma_f32_16x16x32_bf16(ar[mi][0], bb[ni][0], t, 0, 0, 0); \
            t = __builtin_amdgcn_mfma_f32_16x16x32_bf16(ar[mi][1], bb[ni][1], t, 0, 0, 0); \
            acc[(MH)*4 + mi][(NB) + ni] = t; } }

    auto MID = [&]() {
        __builtin_amdgcn_s_barrier();
        asm volatile("s_waitcnt lgkmcnt(0)" ::: "memory");
        __builtin_amdgcn_sched_barrier(0);
        __builtin_amdgcn_s_setprio(1);
    };
    auto END = [&]() {
        __builtin_amdgcn_s_setprio(0);
        __builtin_amdgcn_s_barrier();
        __builtin_amdgcn_sched_barrier(0);
    };

    // ---- prologue: tile0 full -> buf0, tile1 SB -> buf1; retire tile0
    ST_A(0, 0, 0); ST_A(0, 1, 0); ST_B(0, 0, 0); ST_B(0, 1, 0);
    ST_B(1, 0, 1); ST_B(1, 1, 1);
    asm volatile("s_waitcnt vmcnt(4)" ::: "memory");
    __builtin_amdgcn_s_barrier();
    __builtin_amdgcn_sched_barrier(0);

    for (int i = 0; i < NIT; ++i) {
        const int t0 = 2 * i;
        const bool last = (i == NIT - 1);

        // P1
        RD_A(0, 0); RD_BLO(0);
        ST_A(t0 + 1, 0, 1);
        MID(); MQ(blo, 0, 0); END();
        // P2
        RD_BHI(0);
        ST_A(t0 + 1, 1, 1);
        MID(); MQ(bhi, 0, 2); END();
        // P3
        RD_A(0, 1);
        if (!last) ST_B(t0 + 2, 0, 0);
        MID(); MQ(bhi, 1, 2); END();
        // P4
        if (!last) { ST_B(t0 + 2, 1, 0);
                     asm volatile("s_waitcnt vmcnt(4)" ::: "memory"); }
        else       { asm volatile("s_waitcnt vmcnt(0)" ::: "memory"); }
        MID(); MQ(blo, 1, 0); END();
        // P5
        RD_A(1, 0); RD_BLO(1);
        if (!last) ST_A(t0 + 2, 0, 0);
        MID(); MQ(blo, 0, 0); END();
        // P6
        RD_BHI(1);
        if (!last) ST_A(t0 + 2, 1, 0);
        MID(); MQ(bhi, 0, 2); END();
        // P7
        RD_A(1, 1);
        if (!last) ST_B(t0 + 3, 0, 1);
        MID(); MQ(bhi, 1, 2); END();
        // P8
        if (!last) { ST_B(t0 + 3, 1, 1);
                     asm volatile("s_waitcnt vmcnt(4)" ::: "memory"); }
        MID(); MQ(blo, 1, 0); END();
    }

    // ---- epilogue: C/D layout col=lane&15, row=(lane>>4)*4+j
    const int r0 = rowA0 + wm * 128 + ((lane >> 4) << 2);
    const int c0 = ccol0 + wn * 64 + (lane & 15);
    const bool HB = (MODE == 0 || MODE == 3);
#pragma unroll
    for (int ni = 0; ni < 4; ++ni) {
        const int c = c0 + ni * 16;
        const float bv = HB ? bias[c] : 0.0f;
#pragma unroll
        for (int mi = 0; mi < 8; ++mi) {
#pragma unroll
            for (int j = 0; j < 4; ++j) {
                const long r = r0 + mi * 16 + j;
                storev<OutT>(&C[r * (long)ldc + c], acc[mi][ni][j] * scale + bv);
            }
        }
    }
#undef RAF
#undef RBF
#undef RD_A
#undef RD_BLO
#undef RD_BHI
#undef MQ
}

// ---------------- causal row softmax, in place on bf16 scores ----------------
__global__ __launch_bounds__(256) void softmax_causal(bf16* __restrict__ SP, int S) {
    const int i = blockIdx.x;
    bf16* row = SP + ((long)blockIdx.y * S + i) * (long)S;
    const int L = i + 1;
    const int tid = threadIdx.x;
    const int lane = tid & 63, wid = tid >> 6;

    float v[8];
    int nv = 0;
    float m = -3.0e38f;
    for (int j = tid; j < L; j += 256) {
        float x = __bfloat162float(row[j]);
        v[nv++] = x;
        m = fmaxf(m, x);
    }
#pragma unroll
    for (int d = 32; d; d >>= 1) m = fmaxf(m, __shfl_xor(m, d));
    __shared__ float redm[4], reds[4];
    if (lane == 0) redm[wid] = m;
    __syncthreads();
    m = fmaxf(fmaxf(redm[0], redm[1]), fmaxf(redm[2], redm[3]));

    float ssum = 0.f;
    for (int t = 0; t < nv; ++t) { v[t] = __expf(v[t] - m); ssum += v[t]; }
#pragma unroll
    for (int d = 32; d; d >>= 1) ssum += __shfl_xor(ssum, d);
    if (lane == 0) reds[wid] = ssum;
    __syncthreads();
    ssum = reds[0] + reds[1] + reds[2] + reds[3];
    const float inv = 1.0f / ssum;

    nv = 0;
    for (int j = tid; j < L; j += 256) row[j] = __float2bfloat16(v[nv++] * inv);
    const int Lpad = ((i >> 8) + 1) << 8;
    for (int j = L + tid; j < Lpad; j += 256) row[j] = __float2bfloat16(0.0f);
}

// ---------------- bf16 transpose [S,D] -> [D,S] per batch ----------------
__global__ __launch_bounds__(256) void transpose2d(const bf16* __restrict__ V,
                                                   bf16* __restrict__ Vt, int S, int D) {
    __shared__ bf16 t[64][72];
    const long bo = (long)blockIdx.z * (long)S * D;
    const int d0 = blockIdx.x * 64, s0 = blockIdx.y * 64;
    const int tid = threadIdx.x;
    const int r = tid >> 3, c8 = (tid & 7) * 8;
#pragma unroll
    for (int it = 0; it < 2; ++it) {
        const int row = r + it * 32;
        u16x8 val = *(const u16x8*)&V[bo + (long)(s0 + row) * D + d0 + c8];
#pragma unroll
        for (int e = 0; e < 8; ++e) {
            union { unsigned short u; bf16 h; } cv; cv.u = val[e];
            t[row][c8 + e] = cv.h;
        }
    }
    __syncthreads();
#pragma unroll
    for (int it = 0; it < 2; ++it) {
        const int dr = r + it * 32;
        u16x8 o;
#pragma unroll
        for (int e = 0; e < 8; ++e) {
            union { unsigned short u; bf16 h; } cv; cv.h = t[c8 + e][dr];
            o[e] = cv.u;
        }
        *(u16x8*)&Vt[bo + (long)(d0 + dr) * S + s0 + c8] = o;
    }
}

extern "C" void kernel_launch(void* const* d_in, const int* in_sizes, int n_in,
                              void* d_out, int out_size, void* d_ws, size_t ws_size,
                              hipStream_t stream) {
    const int B = 4, S = 2048, D = 1024;
    const long MD = (long)B * S * D;
    const float scale = 0.5f / 32.0f;       // TAU / sqrt(D)

    const float* node  = (const float*)d_in[0];
    const float* label = (const float*)d_in[1];
    const float* Wq = (const float*)d_in[2];
    const float* bq = (const float*)d_in[3];
    const float* Wk = (const float*)d_in[4];
    const float* bk = (const float*)d_in[5];
    const float* Wv = (const float*)d_in[6];
    const float* bv = (const float*)d_in[7];
    const float* Wp = (const float*)d_in[8];
    const float* bp = (const float*)d_in[9];
    float* out = (float*)d_out;

    // ws layout (bytes): nodeb[0,16M) labelb[16M,32M)->Z Wqkv[32M,38M) Wp[38M..)
    // Q[40M,56M)->Vt K[56M,72M) V[72M,88M) SP[88M,120M)
    char* ws = (char*)d_ws;
    bf16* nodeb  = (bf16*)(ws);
    bf16* labelb = (bf16*)(ws + 16777216);
    bf16* Zb     = labelb;                         // alias
    bf16* Wqb = (bf16*)(ws + 33554432);
    bf16* Wkb = (bf16*)(ws + 35651584);
    bf16* Wvb = (bf16*)(ws + 37748736);
    bf16* Wpb = (bf16*)(ws + 39845888);
    bf16* Qb  = (bf16*)(ws + 41943040);
    bf16* Vtb = Qb;                                // alias (transpose after scores)
    bf16* Kb  = (bf16*)(ws + 58720256);
    bf16* Vb  = (bf16*)(ws + 75497472);
    bf16* SP  = (bf16*)(ws + 92274688);
    if (ws_size < 125829120UL) return;

    dim3 blk(256);

    cvt_pair<<<dim3(512, 2), blk, 0, stream>>>(node, label, (u16x8*)nodeb, (u16x8*)labelb, MD / 8);
    cvt_quad<<<dim3(64, 4), blk, 0, stream>>>(Wq, Wk, Wv, Wp,
        (u16x8*)Wqb, (u16x8*)Wkb, (u16x8*)Wvb, (u16x8*)Wpb, (long)D * D / 8);

    // fused QKV: s -> (bm 0..31, bn 0..11); bn segment: 0-3 Q (A=label), 4-7 K, 8-11 V
    gemm256<bf16, 0><<<384, 512, 0, stream>>>(
        labelb, nodeb, Wqb, Qb, Kb, Vb, bq, bk, bv,
        1.0f, D, D, D, D, 0, 0, 0);

    // causal scores = (Q @ K^T) * (TAU/sqrt(d)); 36 lower-tri blocks x 4 batches
    gemm256<bf16, 1><<<144, 512, 0, stream>>>(
        Qb, nullptr, Kb, SP, nullptr, nullptr, nullptr, nullptr, nullptr,
        scale, D, D, D, S, (long)S * D, (long)S * D, (long)S * S);

    // V^T per batch (into dead Q buffer)
    dim3 gtr(D / 64, S / 64, B);
    transpose2d<<<gtr, blk, 0, stream>>>(Vb, Vtb, S, D);

    // causal softmax in-place (zero-fill to 256 boundary)
    softmax_causal<<<dim3(S, B), blk, 0, stream>>>(SP, S);

    // Z = P @ V (as P @ Vt^T), k-tiles causally limited per 256-row block
    gemm256<bf16, 2><<<128, 512, 0, stream>>>(
        SP, nullptr, Vtb, Zb, nullptr, nullptr, nullptr, nullptr, nullptr,
        1.0f, S, S, S, D, (long)S * S, (long)D * S, (long)S * D);

    // out = Z @ Wp^T + bp (fp32)
    gemm256<float, 3><<<128, 512, 0, stream>>>(
        Zb, nullptr, Wpb, out, nullptr, nullptr, bp, nullptr, nullptr,
        1.0f, D, D, D, D, 0, 0, 0);
}

// Round 4
// 187.397 us; speedup vs baseline: 1.4851x; 1.2475x over previous
//
#include <hip/hip_runtime.h>
#include <hip/hip_bf16.h>
#include <stdint.h>

using bf16 = __hip_bfloat16;
typedef __bf16 bf16x8 __attribute__((ext_vector_type(8)));
typedef float f32x4 __attribute__((ext_vector_type(4)));
typedef unsigned short u16x8 __attribute__((ext_vector_type(8)));
typedef unsigned short u16x4 __attribute__((ext_vector_type(4)));

#define AS1 __attribute__((address_space(1)))
#define AS3 __attribute__((address_space(3)))

__device__ inline unsigned short f2b(float f) {
    union { __hip_bfloat16 h; unsigned short u; } cv;
    cv.h = __float2bfloat16(f);
    return cv.u;
}

// ---------------- fp32 -> bf16 converts ----------------
__global__ __launch_bounds__(256) void cvt_pair(const float* __restrict__ a, const float* __restrict__ b,
                                                u16x8* __restrict__ oa, u16x8* __restrict__ ob, long n8) {
    const float* in = blockIdx.y ? b : a;
    u16x8* out = blockIdx.y ? ob : oa;
    long i = (long)blockIdx.x * blockDim.x + threadIdx.x;
    const long stride = (long)gridDim.x * blockDim.x;
    const float4* in4 = (const float4*)in;
    for (; i < n8; i += stride) {
        float4 x = in4[2 * i], y = in4[2 * i + 1];
        u16x8 o;
        o[0] = f2b(x.x); o[1] = f2b(x.y); o[2] = f2b(x.z); o[3] = f2b(x.w);
        o[4] = f2b(y.x); o[5] = f2b(y.y); o[6] = f2b(y.z); o[7] = f2b(y.w);
        out[i] = o;
    }
}

__global__ __launch_bounds__(256) void cvt_quad(const float* __restrict__ a, const float* __restrict__ b,
                                                const float* __restrict__ c, const float* __restrict__ d,
                                                u16x8* __restrict__ oa, u16x8* __restrict__ ob,
                                                u16x8* __restrict__ oc, u16x8* __restrict__ od, long n8) {
    const int y = blockIdx.y;
    const float* in = y == 0 ? a : (y == 1 ? b : (y == 2 ? c : d));
    u16x8* out = y == 0 ? oa : (y == 1 ? ob : (y == 2 ? oc : od));
    long i = (long)blockIdx.x * blockDim.x + threadIdx.x;
    const long stride = (long)gridDim.x * blockDim.x;
    const float4* in4 = (const float4*)in;
    for (; i < n8; i += stride) {
        float4 x = in4[2 * i], z = in4[2 * i + 1];
        u16x8 o;
        o[0] = f2b(x.x); o[1] = f2b(x.y); o[2] = f2b(x.z); o[3] = f2b(x.w);
        o[4] = f2b(z.x); o[5] = f2b(z.y); o[6] = f2b(z.z); o[7] = f2b(z.w);
        out[i] = o;
    }
}

template <typename T> __device__ inline void storev(T* p, float v);
template <> __device__ inline void storev<float>(float* p, float v) { *p = v; }
template <> __device__ inline void storev<bf16>(bf16* p, float v) { *p = __float2bfloat16(v); }

// ================= tiled GEMM: C = A(MxK) * B^T(NxK) =================
// BN=256: 256x256 tile, 8 waves 2Mx4N (per-wave 128x64), 8-phase, LDS 128KB.
// BN=128: 256x128 tile, 8 waves 4Mx2N (per-wave 64x64), 4-phase, LDS 96KB.
// Double-buffered, counted vmcnt across barriers, XOR-swizzled LDS
// (linear gload_lds dest + inverse-swizzled global src + swizzled read),
// counted lgkmcnt split-waits inside heavy-read phases.
// MODE 0: fused K|V projections (B = stacked Wk|Wv rows)
// MODE 1: fused Q | V'=V@Wp^T (seg1 writes V' transposed per batch)
// MODE 2: causal scores (lower-tri grid, batch via decode)
// MODE 3: PV -> final out (fp32) + bias, causal k-limit
template <typename OutT, int MODE, int BN>
__global__ __launch_bounds__(512, 2) void gemmX(
    const bf16* __restrict__ A0, const bf16* __restrict__ A1,
    const bf16* __restrict__ B0p, const bf16* __restrict__ B1p,
    OutT* __restrict__ C0, OutT* __restrict__ C1,
    const float* __restrict__ bias0, const float* __restrict__ bias1,
    float scale, int lda, int ldb, int ldc, int Kdim,
    long sA, long sB, long sC)
{
    constexpr int LDSZ = (BN == 256) ? 131072 : 98304;
    constexpr int BUFS = (BN == 256) ? 65536 : 49152;
    __shared__ __align__(16) char lds[LDSZ];

    // ---- block decode with XCD swizzle (all grids %8 == 0)
    const int nwg = gridDim.x;
    const int bid = blockIdx.x;
    const int s = (nwg & 7) ? bid : ((bid & 7) * (nwg >> 3) + (bid >> 3));

    int bm, ccol0, rowB0, seg = 0;
    const bf16 *A, *B;
    OutT* C;
    const float* bias = nullptr;

    if constexpr (MODE == 0) {                 // K|V: 256 = 32bm x 8bn
        bm = s >> 3; const int bnl = s & 7; seg = bnl >> 2;
        A = A0; B = B0p; rowB0 = bnl * 256;
        C = seg ? C1 : C0; bias = seg ? bias1 : bias0;
        ccol0 = (bnl & 3) * 256;
    } else if constexpr (MODE == 1) {          // Q | VWp: 256 = 2seg x 32bm x 4bn
        seg = s >> 7; const int r = s & 127; bm = r >> 2; const int bn = r & 3;
        A = seg ? A1 : A0; B = seg ? B1p : B0p;
        C = seg ? C1 : C0; bias = seg ? nullptr : bias0;
        rowB0 = bn * 256; ccol0 = bn * 256;
    } else if constexpr (MODE == 2) {          // scores: 144 = 4z x 36tri
        const int z = s / 36, f = s % 36;
        int m = 0;
        while ((m + 1) * (m + 2) / 2 <= f) ++m;
        bm = m; const int bn = f - m * (m + 1) / 2;
        A = A0 + (long)z * sA; B = B0p + (long)z * sB; C = C0 + (long)z * sC;
        rowB0 = bn * 256; ccol0 = bn * 256;
    } else {                                   // PV: 256 = 4z x 8bm x 8bn
        const int z = s >> 6, r = s & 63; bm = r >> 3; const int bn = r & 7;
        A = A0 + (long)z * sA; B = B0p + (long)z * sB; C = C0 + (long)z * sC;
        rowB0 = bn * 128; ccol0 = bn * 128; bias = bias0;
    }

    int KT = Kdim >> 6;
    if constexpr (MODE == 3) { const int lim = 4 * (bm + 1); if (lim < KT) KT = lim; }
    const int NIT = KT >> 1;

    const int tid = threadIdx.x;
    const int lane = tid & 63;
    const int w = tid >> 6;
    constexpr int WR = (BN == 256) ? 128 : 64;
    const int wm = (BN == 256) ? (w >> 2) : (w >> 1);
    const int wn = (BN == 256) ? (w & 3) : (w & 1);

    const int rowA0 = bm * 256;

    // ---- staging (linear LDS dest, inverse-swizzled global source)
    const int rr  = tid >> 3;
    const int lch = (tid & 7) ^ (rr & 7);
    const bf16* gAt = A + (long)(rowA0 + rr) * lda + lch * 8;
    const bf16* gBt = B + (long)(rowB0 + rr) * ldb + lch * 8;

#define LA(b) (lds + (b) * BUFS)
#define LB(b) (lds + 32768 + (b) * BUFS)

    auto SG2 = [&](const bf16* g, int ld, char* dst) {
        __builtin_amdgcn_global_load_lds((const AS1 void*)g,
            (AS3 void*)(dst + tid * 16), 16, 0, 0);
        __builtin_amdgcn_global_load_lds((const AS1 void*)(g + (long)64 * ld),
            (AS3 void*)(dst + 8192 + tid * 16), 16, 0, 0);
    };
    auto ST_A = [&](int kt, int half, int b) {
        SG2(gAt + (long)kt * 64 + (long)half * 128 * lda, lda, LA(b) + half * 16384);
    };
    auto ST_B = [&](int kt, int half, int b) {   // BN=256 halves
        SG2(gBt + (long)kt * 64 + (long)half * 128 * ldb, ldb, LB(b) + half * 16384);
    };
    auto ST_B1 = [&](int kt, int b) {            // BN=128 full B tile
        SG2(gBt + (long)kt * 64, ldb, LB(b));
    };

    // ---- swizzled fragment read addressing
    const int abase = (wm * WR + (lane & 15)) * 128;
    const int bbase = (wn * 64 + (lane & 15)) * 128;
    const int cc0 = (((lane >> 4) << 4)) ^ ((lane & 7) << 4);
    const int cc1 = cc0 ^ 64;

#define RAF(b, mh, mi, kk) (*(const bf16x8*)(LA(b) + abase + (mh)*8192 + (mi)*2048 + ((kk) ? cc1 : cc0)))
#define RBF(b, ni, kk)     (*(const bf16x8*)(LB(b) + bbase + (ni)*2048 + ((kk) ? cc1 : cc0)))

    f32x4 acc[(BN == 256) ? 8 : 4][4] = {};
    bf16x8 ar[4][2], blo[2][2], bhi[2][2];

#define RD_A2(b, mh, MI0) { ar[MI0][0] = RAF(b, mh, MI0, 0); ar[MI0][1] = RAF(b, mh, MI0, 1); \
                            ar[(MI0)+1][0] = RAF(b, mh, (MI0)+1, 0); ar[(MI0)+1][1] = RAF(b, mh, (MI0)+1, 1); }
#define RD_BLO(b)   { blo[0][0] = RBF(b, 0, 0); blo[0][1] = RBF(b, 0, 1); blo[1][0] = RBF(b, 1, 0); blo[1][1] = RBF(b, 1, 1); }
#define RD_BHI(b)   { bhi[0][0] = RBF(b, 2, 0); bhi[0][1] = RBF(b, 2, 1); bhi[1][0] = RBF(b, 3, 0); bhi[1][1] = RBF(b, 3, 1); }

#define MQ1(MI, bb, MH, NB) { \
    f32x4 t0_ = acc[(MH)*4 + (MI)][(NB)]; \
    t0_ = __builtin_amdgcn_mfma_f32_16x16x32_bf16(ar[MI][0], bb[0][0], t0_, 0, 0, 0); \
    t0_ = __builtin_amdgcn_mfma_f32_16x16x32_bf16(ar[MI][1], bb[0][1], t0_, 0, 0, 0); \
    acc[(MH)*4 + (MI)][(NB)] = t0_; \
    f32x4 t1_ = acc[(MH)*4 + (MI)][(NB) + 1]; \
    t1_ = __builtin_amdgcn_mfma_f32_16x16x32_bf16(ar[MI][0], bb[1][0], t1_, 0, 0, 0); \
    t1_ = __builtin_amdgcn_mfma_f32_16x16x32_bf16(ar[MI][1], bb[1][1], t1_, 0, 0, 0); \
    acc[(MH)*4 + (MI)][(NB) + 1] = t1_; }

#define WAIT_LGKM0 { asm volatile("s_waitcnt lgkmcnt(0)" ::: "memory"); __builtin_amdgcn_sched_barrier(0); }
#define WAIT_LGKM4 { asm volatile("s_waitcnt lgkmcnt(4)" ::: "memory"); __builtin_amdgcn_sched_barrier(0); }
#define SCHEDB     __builtin_amdgcn_sched_barrier(0)

    auto BAR = [&]() { __builtin_amdgcn_s_barrier(); SCHEDB; };
    auto PRIO1 = [&]() { __builtin_amdgcn_s_setprio(1); };
    auto PRIO0 = [&]() { __builtin_amdgcn_s_setprio(0); };

    if constexpr (BN == 256) {
        // ---- prologue: tile0 full -> buf0, tile1 SB -> buf1; retire tile0
        ST_A(0, 0, 0); ST_A(0, 1, 0); ST_B(0, 0, 0); ST_B(0, 1, 0);
        ST_B(1, 0, 1); ST_B(1, 1, 1);
        asm volatile("s_waitcnt vmcnt(4)" ::: "memory");
        BAR();

        for (int i = 0; i < NIT; ++i) {
            const int t0 = 2 * i;
            const bool last = (i == NIT - 1);

            // P1: reads [blo, ar01] | [ar23]; MFMA t0 quad (mh0, n-lo)
            RD_BLO(0); RD_A2(0, 0, 0); SCHEDB; RD_A2(0, 0, 2);
            ST_A(t0 + 1, 0, 1);
            BAR(); WAIT_LGKM4; PRIO1();
            MQ1(0, blo, 0, 0); MQ1(1, blo, 0, 0);
            WAIT_LGKM0;
            MQ1(2, blo, 0, 0); MQ1(3, blo, 0, 0);
            PRIO0(); BAR();
            // P2: reads bhi; MFMA (mh0, n-hi)
            RD_BHI(0);
            ST_A(t0 + 1, 1, 1);
            BAR(); WAIT_LGKM0; PRIO1();
            MQ1(0, bhi, 0, 2); MQ1(1, bhi, 0, 2); MQ1(2, bhi, 0, 2); MQ1(3, bhi, 0, 2);
            PRIO0(); BAR();
            // P3: reads ar(mh1) split; MFMA (mh1, n-hi)
            RD_A2(0, 1, 0); SCHEDB; RD_A2(0, 1, 2);
            if (!last) ST_B(t0 + 2, 0, 0);
            BAR(); WAIT_LGKM4; PRIO1();
            MQ1(0, bhi, 1, 2); MQ1(1, bhi, 1, 2);
            WAIT_LGKM0;
            MQ1(2, bhi, 1, 2); MQ1(3, bhi, 1, 2);
            PRIO0(); BAR();
            // P4: MFMA (mh1, n-lo); vmcnt retires tile t0+1
            if (!last) { ST_B(t0 + 2, 1, 0);
                         asm volatile("s_waitcnt vmcnt(4)" ::: "memory"); }
            else       { asm volatile("s_waitcnt vmcnt(0)" ::: "memory"); }
            BAR(); WAIT_LGKM0; PRIO1();
            MQ1(0, blo, 1, 0); MQ1(1, blo, 1, 0); MQ1(2, blo, 1, 0); MQ1(3, blo, 1, 0);
            PRIO0(); BAR();
            // P5
            RD_BLO(1); RD_A2(1, 0, 0); SCHEDB; RD_A2(1, 0, 2);
            if (!last) ST_A(t0 + 2, 0, 0);
            BAR(); WAIT_LGKM4; PRIO1();
            MQ1(0, blo, 0, 0); MQ1(1, blo, 0, 0);
            WAIT_LGKM0;
            MQ1(2, blo, 0, 0); MQ1(3, blo, 0, 0);
            PRIO0(); BAR();
            // P6
            RD_BHI(1);
            if (!last) ST_A(t0 + 2, 1, 0);
            BAR(); WAIT_LGKM0; PRIO1();
            MQ1(0, bhi, 0, 2); MQ1(1, bhi, 0, 2); MQ1(2, bhi, 0, 2); MQ1(3, bhi, 0, 2);
            PRIO0(); BAR();
            // P7
            RD_A2(1, 1, 0); SCHEDB; RD_A2(1, 1, 2);
            if (!last) ST_B(t0 + 3, 0, 1);
            BAR(); WAIT_LGKM4; PRIO1();
            MQ1(0, bhi, 1, 2); MQ1(1, bhi, 1, 2);
            WAIT_LGKM0;
            MQ1(2, bhi, 1, 2); MQ1(3, bhi, 1, 2);
            PRIO0(); BAR();
            // P8
            if (!last) { ST_B(t0 + 3, 1, 1);
                         asm volatile("s_waitcnt vmcnt(4)" ::: "memory"); }
            BAR(); WAIT_LGKM0; PRIO1();
            MQ1(0, blo, 1, 0); MQ1(1, blo, 1, 0); MQ1(2, blo, 1, 0); MQ1(3, blo, 1, 0);
            PRIO0(); BAR();
        }
    } else {
        // ---- BN=128 4-phase. Prologue: tiles 0,1 full; retire tile0.
        ST_A(0, 0, 0); ST_A(0, 1, 0); ST_B1(0, 0);
        ST_A(1, 0, 1); ST_A(1, 1, 1); ST_B1(1, 1);
        asm volatile("s_waitcnt vmcnt(6)" ::: "memory");
        BAR();

        for (int i = 0; i < NIT; ++i) {
            const int t0 = 2 * i;
            const bool last = (i == NIT - 1);

            // P1: reads [blo, ar] | [bhi] from b0; MFMA t0 n-lo
            RD_BLO(0); RD_A2(0, 0, 0); RD_A2(0, 0, 2); SCHEDB; RD_BHI(0);
            BAR(); WAIT_LGKM4; PRIO1();
            MQ1(0, blo, 0, 0); MQ1(1, blo, 0, 0); MQ1(2, blo, 0, 0); MQ1(3, blo, 0, 0);
            PRIO0(); BAR();
            // P2: stage t0+2 A -> b0; retire t0+1; MFMA t0 n-hi
            if (!last) { ST_A(t0 + 2, 0, 0); ST_A(t0 + 2, 1, 0);
                         asm volatile("s_waitcnt vmcnt(4)" ::: "memory"); }
            else       { asm volatile("s_waitcnt vmcnt(0)" ::: "memory"); }
            BAR(); WAIT_LGKM0; PRIO1();
            MQ1(0, bhi, 0, 2); MQ1(1, bhi, 0, 2); MQ1(2, bhi, 0, 2); MQ1(3, bhi, 0, 2);
            PRIO0(); BAR();
            // P3: reads t0+1 from b1; stage t0+2 B -> b0; MFMA t1 n-lo
            RD_BLO(1); RD_A2(1, 0, 0); RD_A2(1, 0, 2); SCHEDB; RD_BHI(1);
            if (!last) ST_B1(t0 + 2, 0);
            BAR(); WAIT_LGKM4; PRIO1();
            MQ1(0, blo, 0, 0); MQ1(1, blo, 0, 0); MQ1(2, blo, 0, 0); MQ1(3, blo, 0, 0);
            PRIO0(); BAR();
            // P4: stage t0+3 full -> b1; retire t0+2; MFMA t1 n-hi
            if (!last) { ST_A(t0 + 3, 0, 1); ST_A(t0 + 3, 1, 1); ST_B1(t0 + 3, 1);
                         asm volatile("s_waitcnt vmcnt(6)" ::: "memory"); }
            BAR(); WAIT_LGKM0; PRIO1();
            MQ1(0, bhi, 0, 2); MQ1(1, bhi, 0, 2); MQ1(2, bhi, 0, 2); MQ1(3, bhi, 0, 2);
            PRIO0(); BAR();
        }
    }

    // ---- epilogue: C/D layout col=lane&15, row=(lane>>4)*4+j
    constexpr int MF = (BN == 256) ? 8 : 4;
    if (MODE == 1 && seg == 1) {
        // V' transposed per-batch: VT[z][c][m%2048], vectorized 8B stores
        const int m0 = rowA0 + wm * WR + ((lane >> 4) << 2);
        const int z2 = m0 >> 11;
        const int lr0 = m0 & 2047;
        bf16* CT = (bf16*)C + (long)z2 * 2097152;
#pragma unroll
        for (int ni = 0; ni < 4; ++ni) {
            const int c = ccol0 + wn * 64 + (lane & 15) + ni * 16;
#pragma unroll
            for (int mi = 0; mi < MF; ++mi) {
                u16x4 o;
                o[0] = f2b(acc[mi][ni][0]); o[1] = f2b(acc[mi][ni][1]);
                o[2] = f2b(acc[mi][ni][2]); o[3] = f2b(acc[mi][ni][3]);
                *(u16x4*)(CT + (long)c * 2048 + lr0 + mi * 16) = o;
            }
        }
    } else {
        const int r0 = rowA0 + wm * WR + ((lane >> 4) << 2);
        const int c0 = ccol0 + wn * 64 + (lane & 15);
        const bool HB = (bias != nullptr);
#pragma unroll
        for (int ni = 0; ni < 4; ++ni) {
            const int c = c0 + ni * 16;
            const float bv = HB ? bias[c] : 0.0f;
#pragma unroll
            for (int mi = 0; mi < MF; ++mi) {
#pragma unroll
                for (int j = 0; j < 4; ++j) {
                    const long r = r0 + mi * 16 + j;
                    storev<OutT>(&C[r * (long)ldc + c], acc[mi][ni][j] * scale + bv);
                }
            }
        }
    }
#undef RAF
#undef RBF
#undef RD_A2
#undef RD_BLO
#undef RD_BHI
#undef MQ1
#undef LA
#undef LB
}

// ---------------- causal row softmax, in place on bf16 scores ----------------
__global__ __launch_bounds__(256) void softmax_causal(bf16* __restrict__ SP, int S) {
    const int i = blockIdx.x;
    bf16* row = SP + ((long)blockIdx.y * S + i) * (long)S;
    const int L = i + 1;
    const int tid = threadIdx.x;
    const int lane = tid & 63, wid = tid >> 6;

    float v[8];
    int nv = 0;
    float m = -3.0e38f;
    for (int j = tid; j < L; j += 256) {
        float x = __bfloat162float(row[j]);
        v[nv++] = x;
        m = fmaxf(m, x);
    }
#pragma unroll
    for (int d = 32; d; d >>= 1) m = fmaxf(m, __shfl_xor(m, d));
    __shared__ float redm[4], reds[4];
    if (lane == 0) redm[wid] = m;
    __syncthreads();
    m = fmaxf(fmaxf(redm[0], redm[1]), fmaxf(redm[2], redm[3]));

    float ssum = 0.f;
    for (int t = 0; t < nv; ++t) { v[t] = __expf(v[t] - m); ssum += v[t]; }
#pragma unroll
    for (int d = 32; d; d >>= 1) ssum += __shfl_xor(ssum, d);
    if (lane == 0) reds[wid] = ssum;
    __syncthreads();
    ssum = reds[0] + reds[1] + reds[2] + reds[3];
    const float inv = 1.0f / ssum;

    nv = 0;
    for (int j = tid; j < L; j += 256) row[j] = __float2bfloat16(v[nv++] * inv);
    const int Lpad = ((i >> 8) + 1) << 8;
    for (int j = L + tid; j < Lpad; j += 256) row[j] = __float2bfloat16(0.0f);
}

extern "C" void kernel_launch(void* const* d_in, const int* in_sizes, int n_in,
                              void* d_out, int out_size, void* d_ws, size_t ws_size,
                              hipStream_t stream) {
    const int B = 4, S = 2048, D = 1024;
    const long MD = (long)B * S * D;
    const float scale = 0.5f / 32.0f;       // TAU / sqrt(D)

    const float* node  = (const float*)d_in[0];
    const float* label = (const float*)d_in[1];
    const float* Wq = (const float*)d_in[2];
    const float* bq = (const float*)d_in[3];
    const float* Wk = (const float*)d_in[4];
    const float* bk = (const float*)d_in[5];
    const float* Wv = (const float*)d_in[6];
    const float* bv = (const float*)d_in[7];
    const float* Wp = (const float*)d_in[8];
    const float* bp = (const float*)d_in[9];
    float* out = (float*)d_out;

    // ws layout: nodeb[0,16M) (dead after KV -> V'T), labelb[16M,32M),
    // Wq[32M) Wk[34M) Wv[36M) Wp[38M) (Wk|Wv stacked for fused KV),
    // Q[40M,56M) K[56M,72M) V[72M,88M) SP[88M,120M)
    char* ws = (char*)d_ws;
    bf16* nodeb  = (bf16*)(ws);
    bf16* VTb    = nodeb;                          // alias (node dead after KV)
    bf16* labelb = (bf16*)(ws + 16777216);
    bf16* Wqb = (bf16*)(ws + 33554432);
    bf16* Wkb = (bf16*)(ws + 35651584);            // Wk|Wv contiguous
    bf16* Wvb = (bf16*)(ws + 37748736);
    bf16* Wpb = (bf16*)(ws + 39845888);
    bf16* Qb  = (bf16*)(ws + 41943040);
    bf16* Kb  = (bf16*)(ws + 58720256);
    bf16* Vb  = (bf16*)(ws + 75497472);
    bf16* SP  = (bf16*)(ws + 92274688);
    if (ws_size < 125829120UL) return;

    dim3 blk(256);

    cvt_pair<<<dim3(512, 2), blk, 0, stream>>>(node, label, (u16x8*)nodeb, (u16x8*)labelb, MD / 8);
    cvt_quad<<<dim3(64, 4), blk, 0, stream>>>(Wq, Wk, Wv, Wp,
        (u16x8*)Wqb, (u16x8*)Wkb, (u16x8*)Wvb, (u16x8*)Wpb, (long)D * D / 8);

    // K|V projections: 256 blocks (exact round); B = stacked Wk|Wv
    gemmX<bf16, 0, 256><<<256, 512, 0, stream>>>(
        nodeb, nullptr, Wkb, nullptr, Kb, Vb, bk, bv,
        1.0f, D, D, D, D, 0, 0, 0);

    // Q | V' = V@Wp^T (transposed write): 128+128 = 256 blocks (exact round)
    gemmX<bf16, 1, 256><<<256, 512, 0, stream>>>(
        labelb, Vb, Wqb, Wpb, Qb, VTb, bq, nullptr,
        1.0f, D, D, D, D, 0, 0, 0);

    // causal scores = (Q @ K^T) * (TAU/sqrt(d)); 36 lower-tri blocks x 4
    gemmX<bf16, 2, 256><<<144, 512, 0, stream>>>(
        Qb, nullptr, Kb, nullptr, SP, nullptr, nullptr, nullptr,
        scale, D, D, S, D, (long)S * D, (long)S * D, (long)S * S);

    // causal softmax in-place (zero-fill to 256 boundary)
    softmax_causal<<<dim3(S, B), blk, 0, stream>>>(SP, S);

    // out = P @ V'^T + bp (fp32), 256x128 tiles, causal k-limit: 256 blocks
    gemmX<float, 3, 128><<<256, 512, 0, stream>>>(
        SP, nullptr, VTb, nullptr, out, nullptr, bp, nullptr,
        1.0f, S, S, D, S, (long)S * S, (long)D * S, (long)S * D);
}